// Round 7
// baseline (350.975 us; speedup 1.0000x reference)
//
#include <hip/hip_runtime.h>

// RobustSum: M = A@V; 3x { dist=cdist(M,V); w=1/(dist+eps); ww=w*A;
//                          M = (ww/rowsum(ww)) @ V }   (T=1.0)
// bf16 MFMA; tolerance = 2% of ref absmax (margin: 5.3x).
//
// Round 7: fix round-6's vprep bug (ty masked with &3 -> only 1/4 of the LDS
// tile written -> transpose read huge stale LDS -> output exploded). The
// single-barrier double-buffered K-loop (BK=32, 2x16 KB) is kept UNCHANGED
// so this round cleanly measures that experiment:
//   barrier(drains tile-k loads issued one compute-phase ago) ->
//   issue tile-k+1 into other buffer -> compute tile k.

typedef __bf16 bf16;
typedef bf16 bf16x4 __attribute__((ext_vector_type(4)));
typedef bf16 bf16x8 __attribute__((ext_vector_type(8)));
typedef float f32x4 __attribute__((ext_vector_type(4)));

#define S_DIM 2048
#define D_DIM 512
#define NB    4
#define EPSILON 0.01f

// ---------------- cast fp32 -> bf16 (vectorized x4) ----------------
__global__ void cast_kernel(const float* __restrict__ in, bf16* __restrict__ out, int n4) {
  int i = blockIdx.x * blockDim.x + threadIdx.x;
  if (i >= n4) return;
  float4 v = ((const float4*)in)[i];
  bf16x4 o = { (bf16)v.x, (bf16)v.y, (bf16)v.z, (bf16)v.w };
  ((bf16x4*)out)[i] = o;
}

// -- V preproc: V fp32 -> Vbf + Vt (bf16) + v2 row L2^2 (of bf16 values) --
__global__ void vprep_kernel(const float* __restrict__ V, bf16* __restrict__ Vbf,
                             bf16* __restrict__ Vt, float* __restrict__ v2) {
  __shared__ float tile[64][68];
  int b  = blockIdx.z;
  int c0 = blockIdx.x * 64;
  int r0 = blockIdx.y * 64;
  const float* Vb = V   + (size_t)b * S_DIM * D_DIM;
  bf16*       Vfb = Vbf + (size_t)b * S_DIM * D_DIM;
  bf16*       Vtb = Vt  + (size_t)b * S_DIM * D_DIM;
  float*      v2b = v2  + (size_t)b * S_DIM;
  int tx = threadIdx.x & 15, ty = threadIdx.x >> 4;   // ty 0..15 (round-6 bug: &3)
#pragma unroll
  for (int i = 0; i < 4; ++i) {
    int r = ty + i * 16;
    float4 v = *(const float4*)(Vb + (size_t)(r0 + r) * D_DIM + (c0 + tx * 4));
    tile[r][tx * 4 + 0] = v.x; tile[r][tx * 4 + 1] = v.y;
    tile[r][tx * 4 + 2] = v.z; tile[r][tx * 4 + 3] = v.w;
    bf16x4 o = { (bf16)v.x, (bf16)v.y, (bf16)v.z, (bf16)v.w };
    *(bf16x4*)(Vfb + (size_t)(r0 + r) * D_DIM + (c0 + tx * 4)) = o;
    float s = 0.f;
#pragma unroll
    for (int j = 0; j < 4; ++j) { float f = (float)o[j]; s += f * f; }
    // threads sharing row r are 16 contiguous lanes of one wave
    s += __shfl_xor(s, 1); s += __shfl_xor(s, 2);
    s += __shfl_xor(s, 4); s += __shfl_xor(s, 8);
    if (tx == 0) atomicAdd(&v2b[r0 + r], s);
  }
  __syncthreads();
#pragma unroll
  for (int i = 0; i < 4; ++i) {
    int c = ty + i * 16;
    bf16x4 o = { (bf16)tile[tx * 4 + 0][c], (bf16)tile[tx * 4 + 1][c],
                 (bf16)tile[tx * 4 + 2][c], (bf16)tile[tx * 4 + 3][c] };
    *(bf16x4*)(Vtb + (size_t)(c0 + c) * S_DIM + (r0 + tx * 4)) = o;
  }
}

// ---------------- NT GEMM: C[M,N] = Amat(MxK) * Bmat(NxK)^T ----------------
// Double-buffered BK=32 K-loop, one barrier per iteration.
// MODE 1: P-GEMM (grid z=NB): dist/weight epilogue -> Wbf + l1p slots (16/row).
// MODE 4: split-K=2 (grid z=2*NB): bf16 partial C, vectorized via LDS quarters.
template <int MODE>
__global__ __launch_bounds__(256, 4)
void gemm_kernel(const bf16* __restrict__ Amat, const bf16* __restrict__ Bmat,
                 int M, int N, int K,
                 bf16* __restrict__ Cp,
                 const float* __restrict__ m2, const float* __restrict__ v2,
                 const bf16* __restrict__ Aw, bf16* __restrict__ Wout,
                 float* __restrict__ l1p) {
  int bz, ks, kbeg, kend;
  if (MODE == 4) { bz = blockIdx.z >> 1; ks = blockIdx.z & 1; kbeg = ks * (K >> 1); kend = kbeg + (K >> 1); }
  else           { bz = blockIdx.z;      ks = 0;              kbeg = 0;             kend = K; }
  const int row0 = blockIdx.y * 128;
  const int col0 = blockIdx.x * 128;
  const bf16* Ab = Amat + (size_t)bz * M * K;
  const bf16* Bb = Bmat + (size_t)bz * N * K;

  // 2 buffers x (ldsA 8192 B + ldsB 8192 B); ldsW (16896 B) unions buffer 0+
  __shared__ char smem[32768];
  float* ldsW = (float*)smem;

  const int tid  = threadIdx.x;
  const int wave = tid >> 6;
  const int lane = tid & 63;
  const int wr   = wave >> 1;
  const int wc   = wave & 1;
  const int q    = lane >> 4;
  const int c16  = lane & 15;

  // staging coords: slot = wave*2+i covers 16 rows x 32 cols (512 elems);
  // lane -> row slot*16 + (lane>>2), col (lane&3)*8; LDS off = lane*16 B.
  const int srow = lane >> 2;
  const int scol = (lane & 3) * 8;

  auto stage = [&](int buf, int k0) {
    bf16* dA = (bf16*)(smem + buf * 16384);
    bf16* dB = (bf16*)(smem + buf * 16384 + 8192);
#pragma unroll
    for (int i = 0; i < 2; ++i) {
      int slot = wave * 2 + i;
      int r = slot * 16 + srow;
      __builtin_amdgcn_global_load_lds(
          (const __attribute__((address_space(1))) void*)(Ab + (size_t)(row0 + r) * K + (k0 + scol)),
          (__attribute__((address_space(3))) void*)(dA + slot * 512), 16, 0, 0);
      __builtin_amdgcn_global_load_lds(
          (const __attribute__((address_space(1))) void*)(Bb + (size_t)(col0 + r) * K + (k0 + scol)),
          (__attribute__((address_space(3))) void*)(dB + slot * 512), 16, 0, 0);
    }
  };

  f32x4 acc[4][4] = {};

  const int nIter = (kend - kbeg) >> 5;
  stage(0, kbeg);
  for (int it = 0; it < nIter; ++it) {
    const int cur = it & 1;
    __syncthreads();                       // drains tile-it loads (issued one
    if (it + 1 < nIter)                    //   compute-phase ago) only
      stage(cur ^ 1, kbeg + ((it + 1) << 5));
    const bf16* lA = (const bf16*)(smem + cur * 16384);
    const bf16* lB = (const bf16*)(smem + cur * 16384 + 8192);
    bf16x8 afr[4], bfr[4];
#pragma unroll
    for (int mt = 0; mt < 4; ++mt)
      afr[mt] = *(const bf16x8*)(lA + (size_t)(wr * 64 + mt * 16 + c16) * 32 + q * 8);
#pragma unroll
    for (int nt = 0; nt < 4; ++nt)
      bfr[nt] = *(const bf16x8*)(lB + (size_t)(wc * 64 + nt * 16 + c16) * 32 + q * 8);
#pragma unroll
    for (int mt = 0; mt < 4; ++mt)
#pragma unroll
      for (int nt = 0; nt < 4; ++nt)
        acc[mt][nt] = __builtin_amdgcn_mfma_f32_16x16x32_bf16(afr[mt], bfr[nt], acc[mt][nt], 0, 0, 0);
  }

  // C/D layout: col = lane&15, row = (lane>>4)*4 + reg (m89-verified)
  const int rowBase = row0 + wr * 64 + q * 4;
  const int colBase = col0 + wc * 64 + c16;

  if (MODE == 1) {
    // phase 1: w = rcp(sqrt(max(m2+v2-2P,0)) + eps), in place (fast approx)
    const float* m2b = m2 + (size_t)bz * M;
    const float* v2b = v2 + (size_t)bz * N;
    float v2v[4];
#pragma unroll
    for (int nt = 0; nt < 4; ++nt) v2v[nt] = v2b[colBase + nt * 16];
#pragma unroll
    for (int mt = 0; mt < 4; ++mt)
#pragma unroll
      for (int r = 0; r < 4; ++r) {
        float m2v = m2b[rowBase + mt * 16 + r];
#pragma unroll
        for (int nt = 0; nt < 4; ++nt) {
          float d2 = fmaxf(m2v + v2v[nt] - 2.f * acc[mt][nt][r], 0.f);
          acc[mt][nt][r] = __builtin_amdgcn_rcpf(__builtin_amdgcn_sqrtf(d2) + EPSILON);
        }
      }
  }

  // phase 2: LDS transpose in 4 quarters of 32 rows -> vectorized global I/O
  const int lr  = tid >> 3;   // 0..31 row within quarter
  const int sub = tid & 7;    // 0..7  16-col chunk
#pragma unroll
  for (int k = 0; k < 4; ++k) {
    __syncthreads();  // protect LDS reuse (staging buffers / previous quarter)
    if (wr == (k >> 1)) {
#pragma unroll
      for (int m = 0; m < 2; ++m) {
        int mt = 2 * (k & 1) + m;
#pragma unroll
        for (int nt = 0; nt < 4; ++nt)
#pragma unroll
          for (int r = 0; r < 4; ++r)
            ldsW[(m * 16 + q * 4 + r) * 132 + wc * 64 + nt * 16 + c16] = acc[mt][nt][r];
      }
    }
    __syncthreads();
    int gi = row0 + 32 * k + lr;
    const float* wp = ldsW + lr * 132 + sub * 16;
    float4 w0 = *(const float4*)(wp + 0);
    float4 w1 = *(const float4*)(wp + 4);
    float4 w2 = *(const float4*)(wp + 8);
    float4 w3 = *(const float4*)(wp + 12);
    float wv_[16] = { w0.x, w0.y, w0.z, w0.w, w1.x, w1.y, w1.z, w1.w,
                      w2.x, w2.y, w2.z, w2.w, w3.x, w3.y, w3.z, w3.w };
    if (MODE == 1) {
      const bf16* ap = Aw + (size_t)bz * M * N + (size_t)gi * N + (col0 + sub * 16);
      bf16x8 a0 = *(const bf16x8*)(ap);
      bf16x8 a1 = *(const bf16x8*)(ap + 8);
      bf16x8 o0, o1;
      float rs = 0.f;
#pragma unroll
      for (int e = 0; e < 8; ++e) {
        float x0 = wv_[e] * (float)a0[e];
        float x1 = wv_[e + 8] * (float)a1[e];
        o0[e] = (bf16)x0; o1[e] = (bf16)x1;
        rs += fabsf(x0) + fabsf(x1);
      }
      bf16* op = Wout + (size_t)bz * M * N + (size_t)gi * N + (col0 + sub * 16);
      *(bf16x8*)(op)     = o0;
      *(bf16x8*)(op + 8) = o1;
      rs += __shfl_xor(rs, 1);
      rs += __shfl_xor(rs, 2);
      rs += __shfl_xor(rs, 4);
      if (sub == 0) l1p[((size_t)blockIdx.x * NB + bz) * M + gi] = rs;
    } else {
      bf16* Cb = Cp + ((size_t)ks * NB + bz) * ((size_t)M * N);
      bf16x8 o0, o1;
#pragma unroll
      for (int e = 0; e < 8; ++e) { o0[e] = (bf16)wv_[e]; o1[e] = (bf16)wv_[e + 8]; }
      bf16* op = Cb + (size_t)gi * N + (col0 + sub * 16);
      *(bf16x8*)(op)     = o0;
      *(bf16x8*)(op + 8) = o1;
    }
  }
}

// ---------------- reduce split-K=2 bf16 partials ----------------
// RMODE 0: Mbf + m2 ;  1: scale 1/l1 -> Mbf + m2 ;  2: scale 1/l1 -> fp32 out
template <int RMODE>
__global__ void reduce_kernel(const bf16* __restrict__ part, const float* __restrict__ l1p,
                              bf16* __restrict__ Mo, float* __restrict__ Fo,
                              float* __restrict__ m2) {
  int wave = threadIdx.x >> 6, lane = threadIdx.x & 63;
  int rg = blockIdx.x * 4 + wave;          // 0..NB*S-1
  const bf16* p0 = part + (size_t)rg * D_DIM + lane * 8;
  const bf16* p1 = p0 + (size_t)NB * S_DIM * D_DIM;
  bf16x8 a = *(const bf16x8*)p0;
  bf16x8 b = *(const bf16x8*)p1;
  float v[8];
#pragma unroll
  for (int e = 0; e < 8; ++e) v[e] = (float)a[e] + (float)b[e];
  float sc = 1.f;
  if (RMODE >= 1) {
    int bb = rg >> 11, row = rg & (S_DIM - 1);
    float l1v = 0.f;
#pragma unroll
    for (int e = 0; e < 16; ++e) l1v += l1p[((size_t)e * NB + bb) * S_DIM + row];
    sc = __builtin_amdgcn_rcpf(fmaxf(l1v, 1e-12f));
  }
  float s = 0.f;
#pragma unroll
  for (int e = 0; e < 8; ++e) { v[e] *= sc; s += v[e] * v[e]; }
  if (RMODE == 2) {
    float4 o0 = { v[0], v[1], v[2], v[3] }, o1 = { v[4], v[5], v[6], v[7] };
    float* op = Fo + (size_t)rg * D_DIM + lane * 8;
    *(float4*)(op) = o0; *(float4*)(op + 4) = o1;
  } else {
    bf16x8 o;
#pragma unroll
    for (int e = 0; e < 8; ++e) o[e] = (bf16)v[e];
    *(bf16x8*)(Mo + (size_t)rg * D_DIM + lane * 8) = o;
#pragma unroll
    for (int off = 32; off > 0; off >>= 1) s += __shfl_xor(s, off);
    if (lane == 0) m2[rg] = s;
  }
}

extern "C" void kernel_launch(void* const* d_in, const int* in_sizes, int n_in,
                              void* d_out, int out_size, void* d_ws, size_t ws_size,
                              hipStream_t stream) {
  const float* A = (const float*)d_in[0];  // (4, 2048, 2048)
  const float* V = (const float*)d_in[1];  // (4, 2048, 512)
  float* out = (float*)d_out;              // (4, 2048, 512) fp32

  char* ws = (char*)d_ws;
  bf16* Abf = (bf16*)ws;   ws += (size_t)NB * S_DIM * S_DIM * 2;       // 33.5 MB
  bf16* Vbf = (bf16*)ws;   ws += (size_t)NB * S_DIM * D_DIM * 2;       //  8.4 MB
  bf16* Vt  = (bf16*)ws;   ws += (size_t)NB * S_DIM * D_DIM * 2;       //  8.4 MB
  bf16* Mbf = (bf16*)ws;   ws += (size_t)NB * S_DIM * D_DIM * 2;       //  8.4 MB
  bf16* Wbf = (bf16*)ws;   ws += (size_t)NB * S_DIM * S_DIM * 2;       // 33.5 MB
  bf16* part = (bf16*)ws;  ws += (size_t)2 * NB * S_DIM * D_DIM * 2;   // 16.8 MB
  float* v2 = (float*)ws;  ws += (size_t)NB * S_DIM * 4;
  float* m2 = (float*)ws;  ws += (size_t)NB * S_DIM * 4;
  float* l1p = (float*)ws; ws += (size_t)16 * NB * S_DIM * 4;          // 512 KB

  int nA4 = NB * S_DIM * S_DIM / 4;
  cast_kernel<<<nA4 / 256, 256, 0, stream>>>(A, Abf, nA4);
  hipMemsetAsync(v2, 0, (size_t)NB * S_DIM * 4, stream);
  vprep_kernel<<<dim3(D_DIM / 64, S_DIM / 64, NB), 256, 0, stream>>>(V, Vbf, Vt, v2);

  // M0 = A @ V  (split-K=2 bf16 partials -> reduce with m2)
  gemm_kernel<4><<<dim3(D_DIM / 128, S_DIM / 128, NB * 2), 256, 0, stream>>>(
      Abf, Vt, S_DIM, D_DIM, S_DIM, part, nullptr, nullptr, nullptr, nullptr, nullptr);
  reduce_kernel<0><<<NB * S_DIM / 4, 256, 0, stream>>>(part, nullptr, Mbf, nullptr, m2);

  for (int it = 0; it < 3; ++it) {
    // P = M @ V^T fused with dist/weight epilogue -> Wbf, l1p
    gemm_kernel<1><<<dim3(S_DIM / 128, S_DIM / 128, NB), 256, 0, stream>>>(
        Mbf, Vbf, S_DIM, S_DIM, D_DIM, nullptr, m2, v2, Abf, Wbf, l1p);
    // M = (W @ V) / l1  (split-K=2 bf16 partials -> reduce)
    gemm_kernel<4><<<dim3(D_DIM / 128, S_DIM / 128, NB * 2), 256, 0, stream>>>(
        Wbf, Vt, S_DIM, D_DIM, S_DIM, part, nullptr, nullptr, nullptr, nullptr, nullptr);
    if (it < 2)
      reduce_kernel<1><<<NB * S_DIM / 4, 256, 0, stream>>>(part, l1p, Mbf, nullptr, m2);
    else
      reduce_kernel<2><<<NB * S_DIM / 4, 256, 0, stream>>>(part, l1p, nullptr, out, nullptr);
  }
}

// Round 8
// 339.312 us; speedup vs baseline: 1.0344x; 1.0344x over previous
//
#include <hip/hip_runtime.h>

// RobustSum: M = A@V; 3x { dist=cdist(M,V); w=1/(dist+eps); ww=w*A;
//                          M = (ww/rowsum(ww)) @ V }   (T=1.0)
// bf16 MFMA; tolerance = 2% of ref absmax (margin: 5.3x).
//
// Round 8: consolidate. (a) K-loop = round-5 exact (BK=64, two-barrier, XOR
// swizzle -- measured best 339us; r7's BK=32 dbuf was 351, prefetch distance
// of one compute phase doesn't cover ~900cyc latency). (b) phase-2 epilogue
// in 2 halves of 64 rows (ldsW 64x132 = 33KB, still 4 blocks/CU) -> 4
// barriers/block instead of 8. (c) vprep: row-stripe blocks, v2 in registers,
// non-atomic store -> memset launch gone.

typedef __bf16 bf16;
typedef bf16 bf16x4 __attribute__((ext_vector_type(4)));
typedef bf16 bf16x8 __attribute__((ext_vector_type(8)));
typedef float f32x4 __attribute__((ext_vector_type(4)));

#define S_DIM 2048
#define D_DIM 512
#define NB    4
#define EPSILON 0.01f

// ---------------- cast fp32 -> bf16 (vectorized x4) ----------------
__global__ void cast_kernel(const float* __restrict__ in, bf16* __restrict__ out, int n4) {
  int i = blockIdx.x * blockDim.x + threadIdx.x;
  if (i >= n4) return;
  float4 v = ((const float4*)in)[i];
  bf16x4 o = { (bf16)v.x, (bf16)v.y, (bf16)v.z, (bf16)v.w };
  ((bf16x4*)out)[i] = o;
}

// -- V preproc: V fp32 -> Vbf + Vt (bf16) + v2 row L2^2 (non-atomic) --
// One block per 64-row stripe; loops over 8 column chunks of 64.
__global__ void vprep_kernel(const float* __restrict__ V, bf16* __restrict__ Vbf,
                             bf16* __restrict__ Vt, float* __restrict__ v2) {
  __shared__ float tile[64][68];
  int b  = blockIdx.y;
  int r0 = blockIdx.x * 64;
  const float* Vb = V   + (size_t)b * S_DIM * D_DIM;
  bf16*       Vfb = Vbf + (size_t)b * S_DIM * D_DIM;
  bf16*       Vtb = Vt  + (size_t)b * S_DIM * D_DIM;
  float*      v2b = v2  + (size_t)b * S_DIM;
  int tx = threadIdx.x & 15, ty = threadIdx.x >> 4;   // ty 0..15
  float acc2[4] = { 0.f, 0.f, 0.f, 0.f };
  for (int c = 0; c < 8; ++c) {
    int c0 = c * 64;
#pragma unroll
    for (int i = 0; i < 4; ++i) {
      int r = ty + i * 16;
      float4 v = *(const float4*)(Vb + (size_t)(r0 + r) * D_DIM + (c0 + tx * 4));
      tile[r][tx * 4 + 0] = v.x; tile[r][tx * 4 + 1] = v.y;
      tile[r][tx * 4 + 2] = v.z; tile[r][tx * 4 + 3] = v.w;
      bf16x4 o = { (bf16)v.x, (bf16)v.y, (bf16)v.z, (bf16)v.w };
      *(bf16x4*)(Vfb + (size_t)(r0 + r) * D_DIM + (c0 + tx * 4)) = o;
#pragma unroll
      for (int j = 0; j < 4; ++j) { float f = (float)o[j]; acc2[i] += f * f; }
    }
    __syncthreads();
#pragma unroll
    for (int i = 0; i < 4; ++i) {
      int cc = ty + i * 16;
      bf16x4 o = { (bf16)tile[tx * 4 + 0][cc], (bf16)tile[tx * 4 + 1][cc],
                   (bf16)tile[tx * 4 + 2][cc], (bf16)tile[tx * 4 + 3][cc] };
      *(bf16x4*)(Vtb + (size_t)(c0 + cc) * S_DIM + (r0 + tx * 4)) = o;
    }
    __syncthreads();   // tile reused next chunk
  }
  // threads sharing row r are 16 contiguous lanes (tid = ty*16+tx)
#pragma unroll
  for (int i = 0; i < 4; ++i) {
    float s = acc2[i];
    s += __shfl_xor(s, 1); s += __shfl_xor(s, 2);
    s += __shfl_xor(s, 4); s += __shfl_xor(s, 8);
    if (tx == 0) v2b[r0 + ty + i * 16] = s;
  }
}

// ---------------- NT GEMM: C[M,N] = Amat(MxK) * Bmat(NxK)^T, BK=64 ----------------
// MODE 1: P-GEMM (grid z=NB): dist/weight epilogue -> Wbf + l1p slots (16/row).
// MODE 4: split-K=2 (grid z=2*NB): bf16 partial C, vectorized via LDS halves.
// LDS swizzle: 16B chunk p within a 128B row holds logical chunk p ^ (row&7).
template <int MODE>
__global__ __launch_bounds__(256, 4)
void gemm_kernel(const bf16* __restrict__ Amat, const bf16* __restrict__ Bmat,
                 int M, int N, int K,
                 bf16* __restrict__ Cp,
                 const float* __restrict__ m2, const float* __restrict__ v2,
                 const bf16* __restrict__ Aw, bf16* __restrict__ Wout,
                 float* __restrict__ l1p) {
  int bz, ks, kbeg, kend;
  if (MODE == 4) { bz = blockIdx.z >> 1; ks = blockIdx.z & 1; kbeg = ks * (K >> 1); kend = kbeg + (K >> 1); }
  else           { bz = blockIdx.z;      ks = 0;              kbeg = 0;             kend = K; }
  const int row0 = blockIdx.y * 128;
  const int col0 = blockIdx.x * 128;
  const bf16* Ab = Amat + (size_t)bz * M * K;
  const bf16* Bb = Bmat + (size_t)bz * N * K;

  // union: staging (2 x 16384 B, 128x64 bf16 each) and epilogue 64x132 fp32
  __shared__ char smem[33792];
  bf16*  ldsA = (bf16*)smem;
  bf16*  ldsB = (bf16*)(smem + 16384);
  float* ldsW = (float*)smem;

  const int tid  = threadIdx.x;
  const int wave = tid >> 6;
  const int lane = tid & 63;
  const int wr   = wave >> 1;
  const int wc   = wave & 1;
  const int q    = lane >> 4;
  const int c16  = lane & 15;

  // staging source coords (swizzled)
  const int srow = lane >> 3;
  const int scol = ((lane & 7) ^ srow) * 8;

  f32x4 acc[4][4] = {};

  for (int k0 = kbeg; k0 < kend; k0 += 64) {
#pragma unroll
    for (int i = 0; i < 4; ++i) {
      int slot = wave * 4 + i;                      // 0..15, 8 rows each
      int r = slot * 8 + srow;
      __builtin_amdgcn_global_load_lds(
          (const __attribute__((address_space(1))) void*)(Ab + (size_t)(row0 + r) * K + (k0 + scol)),
          (__attribute__((address_space(3))) void*)(ldsA + slot * 512), 16, 0, 0);
      __builtin_amdgcn_global_load_lds(
          (const __attribute__((address_space(1))) void*)(Bb + (size_t)(col0 + r) * K + (k0 + scol)),
          (__attribute__((address_space(3))) void*)(ldsB + slot * 512), 16, 0, 0);
    }
    __syncthreads();

#pragma unroll
    for (int kk = 0; kk < 2; ++kk) {
      bf16x8 afr[4], bfr[4];
#pragma unroll
      for (int mt = 0; mt < 4; ++mt) {
        int R = wr * 64 + mt * 16 + c16;
        int p = ((kk << 2) + q) ^ (c16 & 7);
        afr[mt] = *(const bf16x8*)(ldsA + (size_t)R * 64 + p * 8);
      }
#pragma unroll
      for (int nt = 0; nt < 4; ++nt) {
        int R = wc * 64 + nt * 16 + c16;
        int p = ((kk << 2) + q) ^ (c16 & 7);
        bfr[nt] = *(const bf16x8*)(ldsB + (size_t)R * 64 + p * 8);
      }
#pragma unroll
      for (int mt = 0; mt < 4; ++mt)
#pragma unroll
        for (int nt = 0; nt < 4; ++nt)
          acc[mt][nt] = __builtin_amdgcn_mfma_f32_16x16x32_bf16(afr[mt], bfr[nt], acc[mt][nt], 0, 0, 0);
    }
    __syncthreads();
  }

  // C/D layout: col = lane&15, row = (lane>>4)*4 + reg (m89-verified)
  const int rowBase = row0 + wr * 64 + q * 4;
  const int colBase = col0 + wc * 64 + c16;

  if (MODE == 1) {
    // phase 1: w = rcp(sqrt(max(m2+v2-2P,0)) + eps), in place (fast approx)
    const float* m2b = m2 + (size_t)bz * M;
    const float* v2b = v2 + (size_t)bz * N;
    float v2v[4];
#pragma unroll
    for (int nt = 0; nt < 4; ++nt) v2v[nt] = v2b[colBase + nt * 16];
#pragma unroll
    for (int mt = 0; mt < 4; ++mt)
#pragma unroll
      for (int r = 0; r < 4; ++r) {
        float m2v = m2b[rowBase + mt * 16 + r];
#pragma unroll
        for (int nt = 0; nt < 4; ++nt) {
          float d2 = fmaxf(m2v + v2v[nt] - 2.f * acc[mt][nt][r], 0.f);
          acc[mt][nt][r] = __builtin_amdgcn_rcpf(__builtin_amdgcn_sqrtf(d2) + EPSILON);
        }
      }
  }

  // phase 2: LDS transpose in 2 halves of 64 rows -> vectorized global I/O
  const int lr  = tid >> 3;   // 0..31
  const int sub = tid & 7;    // 0..7  16-col chunk
#pragma unroll
  for (int h = 0; h < 2; ++h) {
    __syncthreads();  // protect LDS reuse (staging buffers / previous half)
    if (wr == h) {
#pragma unroll
      for (int mt = 0; mt < 4; ++mt)
#pragma unroll
        for (int nt = 0; nt < 4; ++nt)
#pragma unroll
          for (int r = 0; r < 4; ++r)
            ldsW[(mt * 16 + q * 4 + r) * 132 + wc * 64 + nt * 16 + c16] = acc[mt][nt][r];
    }
    __syncthreads();
#pragma unroll
    for (int h2 = 0; h2 < 2; ++h2) {
      int rloc = lr + 32 * h2;            // 0..63
      int gi = row0 + 64 * h + rloc;
      const float* wp = ldsW + rloc * 132 + sub * 16;
      float4 w0 = *(const float4*)(wp + 0);
      float4 w1 = *(const float4*)(wp + 4);
      float4 w2 = *(const float4*)(wp + 8);
      float4 w3 = *(const float4*)(wp + 12);
      float wv_[16] = { w0.x, w0.y, w0.z, w0.w, w1.x, w1.y, w1.z, w1.w,
                        w2.x, w2.y, w2.z, w2.w, w3.x, w3.y, w3.z, w3.w };
      if (MODE == 1) {
        const bf16* ap = Aw + (size_t)bz * M * N + (size_t)gi * N + (col0 + sub * 16);
        bf16x8 a0 = *(const bf16x8*)(ap);
        bf16x8 a1 = *(const bf16x8*)(ap + 8);
        bf16x8 o0, o1;
        float rs = 0.f;
#pragma unroll
        for (int e = 0; e < 8; ++e) {
          float x0 = wv_[e] * (float)a0[e];
          float x1 = wv_[e + 8] * (float)a1[e];
          o0[e] = (bf16)x0; o1[e] = (bf16)x1;
          rs += fabsf(x0) + fabsf(x1);
        }
        bf16* op = Wout + (size_t)bz * M * N + (size_t)gi * N + (col0 + sub * 16);
        *(bf16x8*)(op)     = o0;
        *(bf16x8*)(op + 8) = o1;
        rs += __shfl_xor(rs, 1);
        rs += __shfl_xor(rs, 2);
        rs += __shfl_xor(rs, 4);
        if (sub == 0) l1p[((size_t)blockIdx.x * NB + bz) * M + gi] = rs;
      } else {
        bf16* Cb = Cp + ((size_t)ks * NB + bz) * ((size_t)M * N);
        bf16x8 o0, o1;
#pragma unroll
        for (int e = 0; e < 8; ++e) { o0[e] = (bf16)wv_[e]; o1[e] = (bf16)wv_[e + 8]; }
        bf16* op = Cb + (size_t)gi * N + (col0 + sub * 16);
        *(bf16x8*)(op)     = o0;
        *(bf16x8*)(op + 8) = o1;
      }
    }
  }
}

// ---------------- reduce split-K=2 bf16 partials ----------------
// RMODE 0: Mbf + m2 ;  1: scale 1/l1 -> Mbf + m2 ;  2: scale 1/l1 -> fp32 out
template <int RMODE>
__global__ void reduce_kernel(const bf16* __restrict__ part, const float* __restrict__ l1p,
                              bf16* __restrict__ Mo, float* __restrict__ Fo,
                              float* __restrict__ m2) {
  int wave = threadIdx.x >> 6, lane = threadIdx.x & 63;
  int rg = blockIdx.x * 4 + wave;          // 0..NB*S-1
  const bf16* p0 = part + (size_t)rg * D_DIM + lane * 8;
  const bf16* p1 = p0 + (size_t)NB * S_DIM * D_DIM;
  bf16x8 a = *(const bf16x8*)p0;
  bf16x8 b = *(const bf16x8*)p1;
  float v[8];
#pragma unroll
  for (int e = 0; e < 8; ++e) v[e] = (float)a[e] + (float)b[e];
  float sc = 1.f;
  if (RMODE >= 1) {
    int bb = rg >> 11, row = rg & (S_DIM - 1);
    float l1v = 0.f;
#pragma unroll
    for (int e = 0; e < 16; ++e) l1v += l1p[((size_t)e * NB + bb) * S_DIM + row];
    sc = __builtin_amdgcn_rcpf(fmaxf(l1v, 1e-12f));
  }
  float s = 0.f;
#pragma unroll
  for (int e = 0; e < 8; ++e) { v[e] *= sc; s += v[e] * v[e]; }
  if (RMODE == 2) {
    float4 o0 = { v[0], v[1], v[2], v[3] }, o1 = { v[4], v[5], v[6], v[7] };
    float* op = Fo + (size_t)rg * D_DIM + lane * 8;
    *(float4*)(op) = o0; *(float4*)(op + 4) = o1;
  } else {
    bf16x8 o;
#pragma unroll
    for (int e = 0; e < 8; ++e) o[e] = (bf16)v[e];
    *(bf16x8*)(Mo + (size_t)rg * D_DIM + lane * 8) = o;
#pragma unroll
    for (int off = 32; off > 0; off >>= 1) s += __shfl_xor(s, off);
    if (lane == 0) m2[rg] = s;
  }
}

extern "C" void kernel_launch(void* const* d_in, const int* in_sizes, int n_in,
                              void* d_out, int out_size, void* d_ws, size_t ws_size,
                              hipStream_t stream) {
  const float* A = (const float*)d_in[0];  // (4, 2048, 2048)
  const float* V = (const float*)d_in[1];  // (4, 2048, 512)
  float* out = (float*)d_out;              // (4, 2048, 512) fp32

  char* ws = (char*)d_ws;
  bf16* Abf = (bf16*)ws;   ws += (size_t)NB * S_DIM * S_DIM * 2;       // 33.5 MB
  bf16* Vbf = (bf16*)ws;   ws += (size_t)NB * S_DIM * D_DIM * 2;       //  8.4 MB
  bf16* Vt  = (bf16*)ws;   ws += (size_t)NB * S_DIM * D_DIM * 2;       //  8.4 MB
  bf16* Mbf = (bf16*)ws;   ws += (size_t)NB * S_DIM * D_DIM * 2;       //  8.4 MB
  bf16* Wbf = (bf16*)ws;   ws += (size_t)NB * S_DIM * S_DIM * 2;       // 33.5 MB
  bf16* part = (bf16*)ws;  ws += (size_t)2 * NB * S_DIM * D_DIM * 2;   // 16.8 MB
  float* v2 = (float*)ws;  ws += (size_t)NB * S_DIM * 4;
  float* m2 = (float*)ws;  ws += (size_t)NB * S_DIM * 4;
  float* l1p = (float*)ws; ws += (size_t)16 * NB * S_DIM * 4;          // 512 KB

  int nA4 = NB * S_DIM * S_DIM / 4;
  cast_kernel<<<nA4 / 256, 256, 0, stream>>>(A, Abf, nA4);
  vprep_kernel<<<dim3(S_DIM / 64, NB), 256, 0, stream>>>(V, Vbf, Vt, v2);

  // M0 = A @ V  (split-K=2 bf16 partials -> reduce with m2)
  gemm_kernel<4><<<dim3(D_DIM / 128, S_DIM / 128, NB * 2), 256, 0, stream>>>(
      Abf, Vt, S_DIM, D_DIM, S_DIM, part, nullptr, nullptr, nullptr, nullptr, nullptr);
  reduce_kernel<0><<<NB * S_DIM / 4, 256, 0, stream>>>(part, nullptr, Mbf, nullptr, m2);

  for (int it = 0; it < 3; ++it) {
    // P = M @ V^T fused with dist/weight epilogue -> Wbf, l1p
    gemm_kernel<1><<<dim3(S_DIM / 128, S_DIM / 128, NB), 256, 0, stream>>>(
        Mbf, Vbf, S_DIM, S_DIM, D_DIM, nullptr, m2, v2, Abf, Wbf, l1p);
    // M = (W @ V) / l1  (split-K=2 bf16 partials -> reduce)
    gemm_kernel<4><<<dim3(D_DIM / 128, S_DIM / 128, NB * 2), 256, 0, stream>>>(
        Wbf, Vt, S_DIM, D_DIM, S_DIM, part, nullptr, nullptr, nullptr, nullptr, nullptr);
    if (it < 2)
      reduce_kernel<1><<<NB * S_DIM / 4, 256, 0, stream>>>(part, l1p, Mbf, nullptr, m2);
    else
      reduce_kernel<2><<<NB * S_DIM / 4, 256, 0, stream>>>(part, l1p, nullptr, out, nullptr);
  }
}